// Round 7
// baseline (575.779 us; speedup 1.0000x reference)
//
#include <hip/hip_runtime.h>

typedef __bf16 bf16;
typedef bf16 bf16x4 __attribute__((ext_vector_type(4)));
typedef bf16 bf16x8 __attribute__((ext_vector_type(8)));
typedef float f32x4 __attribute__((ext_vector_type(4)));

// ws layout: bf16 elements 0..163839 = transposed weights; then fp32 qg[64][256]
#define WS_WREL_T  0
#define WS_WNODE_T 16384
#define WS_W1T     32768
#define WS_W2T     98304
#define WS_QG_F    163840   // (float*)(ws + WS_QG_F)

// ---------- prep: transpose weights to B^T (N-major) bf16 ----------
__global__ void prep_weights(const float* __restrict__ Wrel,
                             const float* __restrict__ Wnode,
                             const float* __restrict__ W1,
                             const float* __restrict__ W2,
                             bf16* __restrict__ ws) {
  int id = blockIdx.x * 256 + threadIdx.x;
  if (id < 16384) {
    ws[WS_WREL_T + id] = (bf16)Wrel[(id & 127) * 128 + (id >> 7)];
  } else if (id < 32768) {
    int j = id - 16384;
    ws[WS_WNODE_T + j] = (bf16)Wnode[(j & 127) * 128 + (j >> 7)];
  } else if (id < 98304) {
    int j = id - 32768;
    ws[WS_W1T + j] = (bf16)W1[(j & 255) * 256 + (j >> 8)];
  } else if (id < 163840) {
    int j = id - 98304;
    ws[WS_W2T + j] = (bf16)W2[(j & 255) * 256 + (j >> 8)];
  }
}

// ---------- prep: qg[64][256] = sigmoid(question @ W_qgate), fp32 ----------
__global__ void prep_qg(const float* __restrict__ question,
                        const float* __restrict__ Wq,
                        float* __restrict__ qgf) {
  int b = blockIdx.x, c = threadIdx.x;
  float s = 0.f;
#pragma unroll 8
  for (int k = 0; k < 128; ++k) s += question[b * 128 + k] * Wq[k * 256 + c];
  qgf[b * 256 + c] = 1.f / (1.f + expf(-s));
}

// tanh-form GELU: max |diff vs erf-GELU| ~5e-4, far under threshold
__device__ __forceinline__ float gelu_fast(float x) {
  float x2 = x * x;
  float p = fmaf(0.0356774081f, x2, 0.7978845608f);
  float y = p * x;
  float e = __expf(2.f * y);
  float r = __builtin_amdgcn_rcpf(e + 1.f);
  float th = 1.f - 2.f * r;
  return 0.5f * x * (1.f + th);
}

// ---------- main: 32 edges/block, 4 waves, swapped-operand MFMA ----------
// D = W_frag x X_frag so D = (X @ W)^T fragments: lane holds one edge and 4
// consecutive OUTPUT columns -> vectorized gate loads / LDS writes / stores.
// BM=32 keeps LDS at 16.6KB -> ~6 blocks/CU resident (latency hiding).
__global__ __launch_bounds__(256, 3) void fused_main(
    const float* __restrict__ rel_tok,   // [E,128]
    const float* __restrict__ node_tok,  // [N,128]
    const int*   __restrict__ tail_idx,  // edge_index + E
    const int*   __restrict__ ebatch,    // [E]
    const bf16*  __restrict__ Wrel_t,    // [128][128]  [n][k]
    const bf16*  __restrict__ Wnode_t,   // [128][128]
    const bf16*  __restrict__ W1t,       // [256][256]
    const bf16*  __restrict__ W2t,       // [256][256]
    const float* __restrict__ qgf,       // [64][256] fp32
    const float* __restrict__ b1,
    const float* __restrict__ b2,
    float* __restrict__ out)             // [E,256]
{
  // One 16KB union buffer:
  //  T : tokens [2][32][128] bf16, byte = h*8192 + row*256 + ((2k)^((row&7)<<4))
  //  AK/H:      [32][256]    bf16, byte = row*512 + ((2c)^((row&7)<<4))
  __shared__ char s_buf[16384];
  __shared__ int  s_eb[32];

  const int tid = threadIdx.x;
  const int w  = tid >> 6;     // wave 0..3
  const int l  = tid & 63;
  const int lo = l & 15;
  const int hi = l >> 4;
  const int base = blockIdx.x * 32;

  if (tid < 32) s_eb[tid] = ebatch[base + tid];

  // bias fragments (4 consecutive floats per lane), constant per block
  float4 b1v[4], b2v[4];
#pragma unroll
  for (int ai = 0; ai < 4; ++ai) {
    b1v[ai] = *(const float4*)(b1 + w * 64 + ai * 16 + hi * 4);
    b2v[ai] = *(const float4*)(b2 + w * 64 + ai * 16 + hi * 4);
  }

  // ---- stage tokens -> LDS bf16 (swizzled) ----
  {
    const float4* g = (const float4*)rel_tok + (size_t)base * 32;
#pragma unroll
    for (int i = 0; i < 4; ++i) {
      int idx = tid + i * 256;          // over [32][32] float4
      int row = idx >> 5, c4 = idx & 31;
      float4 v = g[idx];
      bf16x4 b; b[0] = (bf16)v.x; b[1] = (bf16)v.y; b[2] = (bf16)v.z; b[3] = (bf16)v.w;
      int off = row * 256 + ((c4 * 8) ^ ((row & 7) << 4));
      *(bf16x4*)(s_buf + off) = b;
    }
#pragma unroll
    for (int i = 0; i < 4; ++i) {
      int idx = tid + i * 256;
      int row = idx >> 5, c4 = idx & 31;
      int tail = tail_idx[base + row];  // 32 lanes same addr
      float4 v = ((const float4*)node_tok)[(size_t)tail * 32 + c4];
      bf16x4 b; b[0] = (bf16)v.x; b[1] = (bf16)v.y; b[2] = (bf16)v.z; b[3] = (bf16)v.w;
      int off = 8192 + row * 256 + ((c4 * 8) ^ ((row & 7) << 4));
      *(bf16x4*)(s_buf + off) = b;
    }
  }
  __syncthreads();                       // B_a: tokens + s_eb visible

  const f32x4 zero4 = {0.f, 0.f, 0.f, 0.f};

  // ---- GEMM1 (swapped): waves 0,1 -> rel (h=0); 2,3 -> node (h=1) ----
  const int h1 = w >> 1;
  const bf16* Wt = h1 ? Wnode_t : Wrel_t;
  const int nb = (w & 1) * 64;           // ncol base within this half
  f32x4 acc1[4][2];                      // [ai=ncol tile][bj=edge tile]
#pragma unroll
  for (int ai = 0; ai < 4; ++ai)
#pragma unroll
    for (int bj = 0; bj < 2; ++bj) acc1[ai][bj] = zero4;

#pragma unroll
  for (int kk = 0; kk < 4; ++kk) {
    const int k0 = kk * 32 + hi * 8;
    bf16x8 a[4];
#pragma unroll
    for (int ai = 0; ai < 4; ++ai)
      a[ai] = *(const bf16x8*)(Wt + (nb + ai * 16 + lo) * 128 + k0);
#pragma unroll
    for (int bj = 0; bj < 2; ++bj) {
      int e = bj * 16 + lo;
      bf16x8 b = *(const bf16x8*)(s_buf + h1 * 8192 + e * 256 + ((2 * k0) ^ ((e & 7) << 4)));
#pragma unroll
      for (int ai = 0; ai < 4; ++ai)
        acc1[ai][bj] = __builtin_amdgcn_mfma_f32_16x16x32_bf16(a[ai], b, acc1[ai][bj], 0, 0, 0);
    }
  }
  __syncthreads();                       // B_b: token reads done

  // gate + pack -> AK (row-major [edge][256] swizzled), vectorized b64 writes
#pragma unroll
  for (int bj = 0; bj < 2; ++bj) {
    int e = bj * 16 + lo;
    int qrow = s_eb[e] * 256;
#pragma unroll
    for (int ai = 0; ai < 4; ++ai) {
      int col0 = h1 * 128 + (w & 1) * 64 + ai * 16 + hi * 4;
      float4 g = *(const float4*)(qgf + qrow + col0);
      bf16x4 pk;
      pk[0] = (bf16)(acc1[ai][bj][0] * g.x);
      pk[1] = (bf16)(acc1[ai][bj][1] * g.y);
      pk[2] = (bf16)(acc1[ai][bj][2] * g.z);
      pk[3] = (bf16)(acc1[ai][bj][3] * g.w);
      int off = e * 512 + ((2 * col0) ^ ((e & 7) << 4));
      *(bf16x4*)(s_buf + off) = pk;
    }
  }
  __syncthreads();                       // B_c: AK visible

  // ---- GEMM2 (swapped): H^T frags = W1 x AK^T ----
  f32x4 acc2[4][2];
#pragma unroll
  for (int ai = 0; ai < 4; ++ai)
#pragma unroll
    for (int bj = 0; bj < 2; ++bj) acc2[ai][bj] = zero4;

#pragma unroll
  for (int kk = 0; kk < 8; ++kk) {
    const int k0 = kk * 32 + hi * 8;
    bf16x8 a[4];
#pragma unroll
    for (int ai = 0; ai < 4; ++ai)
      a[ai] = *(const bf16x8*)(W1t + (w * 64 + ai * 16 + lo) * 256 + k0);
#pragma unroll
    for (int bj = 0; bj < 2; ++bj) {
      int e = bj * 16 + lo;
      bf16x8 b = *(const bf16x8*)(s_buf + e * 512 + ((2 * k0) ^ ((e & 7) << 4)));
#pragma unroll
      for (int ai = 0; ai < 4; ++ai)
        acc2[ai][bj] = __builtin_amdgcn_mfma_f32_16x16x32_bf16(a[ai], b, acc2[ai][bj], 0, 0, 0);
    }
  }
  __syncthreads();                       // B_d: AK reads done

  // gelu + bias -> H (same layout as AK)
#pragma unroll
  for (int bj = 0; bj < 2; ++bj) {
    int e = bj * 16 + lo;
#pragma unroll
    for (int ai = 0; ai < 4; ++ai) {
      int col0 = w * 64 + ai * 16 + hi * 4;
      bf16x4 pk;
      pk[0] = (bf16)gelu_fast(acc2[ai][bj][0] + b1v[ai].x);
      pk[1] = (bf16)gelu_fast(acc2[ai][bj][1] + b1v[ai].y);
      pk[2] = (bf16)gelu_fast(acc2[ai][bj][2] + b1v[ai].z);
      pk[3] = (bf16)gelu_fast(acc2[ai][bj][3] + b1v[ai].w);
      int off = e * 512 + ((2 * col0) ^ ((e & 7) << 4));
      *(bf16x4*)(s_buf + off) = pk;
    }
  }
  __syncthreads();                       // B_e: H visible

  // ---- GEMM3 (swapped): out^T frags = W2 x H^T ----
  f32x4 acc3[4][2];
#pragma unroll
  for (int ai = 0; ai < 4; ++ai)
#pragma unroll
    for (int bj = 0; bj < 2; ++bj) acc3[ai][bj] = zero4;

#pragma unroll
  for (int kk = 0; kk < 8; ++kk) {
    const int k0 = kk * 32 + hi * 8;
    bf16x8 a[4];
#pragma unroll
    for (int ai = 0; ai < 4; ++ai)
      a[ai] = *(const bf16x8*)(W2t + (w * 64 + ai * 16 + lo) * 256 + k0);
#pragma unroll
    for (int bj = 0; bj < 2; ++bj) {
      int e = bj * 16 + lo;
      bf16x8 b = *(const bf16x8*)(s_buf + e * 512 + ((2 * k0) ^ ((e & 7) << 4)));
#pragma unroll
      for (int ai = 0; ai < 4; ++ai)
        acc3[ai][bj] = __builtin_amdgcn_mfma_f32_16x16x32_bf16(a[ai], b, acc3[ai][bj], 0, 0, 0);
    }
  }

  // bias + store: one float4 per fragment; lanes hi=0..3 form 64B runs
#pragma unroll
  for (int bj = 0; bj < 2; ++bj) {
    int e = bj * 16 + lo;
#pragma unroll
    for (int ai = 0; ai < 4; ++ai) {
      int col0 = w * 64 + ai * 16 + hi * 4;
      float4 o;
      o.x = acc3[ai][bj][0] + b2v[ai].x;
      o.y = acc3[ai][bj][1] + b2v[ai].y;
      o.z = acc3[ai][bj][2] + b2v[ai].z;
      o.w = acc3[ai][bj][3] + b2v[ai].w;
      *(float4*)(out + (size_t)(base + e) * 256 + col0) = o;
    }
  }
}

extern "C" void kernel_launch(void* const* d_in, const int* in_sizes, int n_in,
                              void* d_out, int out_size, void* d_ws, size_t ws_size,
                              hipStream_t stream) {
  const float* rel    = (const float*)d_in[0];
  const float* node   = (const float*)d_in[1];
  const int*   eidx   = (const int*)d_in[2];
  const float* quest  = (const float*)d_in[3];
  const int*   ebat   = (const int*)d_in[4];
  const float* Wrel   = (const float*)d_in[5];
  const float* Wnode  = (const float*)d_in[6];
  const float* Wq     = (const float*)d_in[7];
  const float* W1     = (const float*)d_in[8];
  const float* bias1  = (const float*)d_in[9];
  const float* W2     = (const float*)d_in[10];
  const float* bias2  = (const float*)d_in[11];
  float* outp = (float*)d_out;
  bf16* ws = (bf16*)d_ws;
  float* qgf = (float*)(ws + WS_QG_F);

  const int E = in_sizes[4];  // 400000

  prep_weights<<<640, 256, 0, stream>>>(Wrel, Wnode, W1, W2, ws);
  prep_qg<<<64, 256, 0, stream>>>(quest, Wq, qgf);
  fused_main<<<E / 32, 256, 0, stream>>>(
      rel, node, eidx + E, ebat,
      ws + WS_WREL_T, ws + WS_WNODE_T, ws + WS_W1T, ws + WS_W2T, qgf,
      bias1, bias2, outp);
}

// Round 8
// 317.712 us; speedup vs baseline: 1.8123x; 1.8123x over previous
//
#include <hip/hip_runtime.h>

typedef __bf16 bf16;
typedef bf16 bf16x4 __attribute__((ext_vector_type(4)));
typedef bf16 bf16x8 __attribute__((ext_vector_type(8)));
typedef float f32x4 __attribute__((ext_vector_type(4)));

// ws layout (bf16 elements):
//   PK1 [4][4][4][64][8]  = 32768   (GEMM1 weights, fragment-packed)
//   PK2 [4][8][4][64][8]  = 65536   (W1)
//   PK3 [4][8][4][64][8]  = 65536   (W2)
//   QG  float[64][256]              (gate table)
#define WS_PK1   0
#define WS_PK2   32768
#define WS_PK3   98304
#define WS_QG_F  163840

// ---------- prep: pack weights into per-(cg,kk,ai) contiguous 1KB fragments ----------
// Fragment element for lane l=(hi,lo), reg j:  W[k][n],
//   n = colbase + ai*16 + lo,  k = kk*32 + hi*8 + j
__global__ void prep_weights(const float* __restrict__ Wrel,
                             const float* __restrict__ Wnode,
                             const float* __restrict__ W1,
                             const float* __restrict__ W2,
                             bf16* __restrict__ ws) {
  int id = blockIdx.x * 256 + threadIdx.x;
  if (id < 32768) {                       // PK1: cg(4) kk(4) ai(4) l(64) j(8)
    int cg = id >> 13, rem = id & 8191;
    int kk = rem >> 11;
    int ai = (rem >> 9) & 3;
    int l  = (rem >> 3) & 63;
    int j  = rem & 7;
    int n  = (cg & 1) * 64 + ai * 16 + (l & 15);
    int k  = kk * 32 + (l >> 4) * 8 + j;
    const float* src = (cg >> 1) ? Wnode : Wrel;
    ws[WS_PK1 + id] = (bf16)src[k * 128 + n];
  } else if (id < 98304) {                // PK2: cg(4) kk(8) ai(4) l(64) j(8)
    int t = id - 32768;
    int cg = t >> 14, rem = t & 16383;
    int kk = rem >> 11;
    int ai = (rem >> 9) & 3;
    int l  = (rem >> 3) & 63;
    int j  = rem & 7;
    int n  = cg * 64 + ai * 16 + (l & 15);
    int k  = kk * 32 + (l >> 4) * 8 + j;
    ws[WS_PK2 + t] = (bf16)W1[k * 256 + n];
  } else if (id < 163840) {               // PK3
    int t = id - 98304;
    int cg = t >> 14, rem = t & 16383;
    int kk = rem >> 11;
    int ai = (rem >> 9) & 3;
    int l  = (rem >> 3) & 63;
    int j  = rem & 7;
    int n  = cg * 64 + ai * 16 + (l & 15);
    int k  = kk * 32 + (l >> 4) * 8 + j;
    ws[WS_PK3 + t] = (bf16)W2[k * 256 + n];
  }
}

// ---------- prep: qg[64][256] = sigmoid(question @ W_qgate), fp32 ----------
__global__ void prep_qg(const float* __restrict__ question,
                        const float* __restrict__ Wq,
                        float* __restrict__ qgf) {
  int b = blockIdx.x, c = threadIdx.x;
  float s = 0.f;
#pragma unroll 8
  for (int k = 0; k < 128; ++k) s += question[b * 128 + k] * Wq[k * 256 + c];
  qgf[b * 256 + c] = 1.f / (1.f + expf(-s));
}

// tanh-form GELU: max |diff vs erf-GELU| ~5e-4, far under 1.23e-2 budget
__device__ __forceinline__ float gelu_fast(float x) {
  float x2 = x * x;
  float p = fmaf(0.0356774081f, x2, 0.7978845608f);
  float y = p * x;
  float e = __expf(2.f * y);
  float r = __builtin_amdgcn_rcpf(e + 1.f);
  float th = 1.f - 2.f * r;
  return 0.5f * x * (1.f + th);
}

// ---------- main: 128 edges/block, 8 waves = (edge-half) x (col-group) ----------
// Swapped-operand MFMA (D = W x X^T). Twin waves (eh=0/1, same cg) read the
// IDENTICAL packed weight stream between the same barriers -> L1 dedup.
__global__ __launch_bounds__(512, 4) void fused_main(
    const float* __restrict__ rel_tok,   // [E,128]
    const float* __restrict__ node_tok,  // [N,128]
    const int*   __restrict__ tail_idx,  // edge_index + E
    const int*   __restrict__ ebatch,    // [E]
    const bf16*  __restrict__ pk1,       // packed GEMM1 weights
    const bf16*  __restrict__ pk2,       // packed W1
    const bf16*  __restrict__ pk3,       // packed W2
    const float* __restrict__ qgf,       // [64][256] fp32
    const float* __restrict__ b1,
    const float* __restrict__ b2,
    float* __restrict__ out)             // [E,256]
{
  // 64KB union buffer:
  //  T : tokens [2][128][128] bf16, byte = h*32768 + e*256 + ((2k)^((e&7)<<4))
  //  AK/H:      [128][256]    bf16, byte = e*512  + ((2c)^((e&7)<<4))
  __shared__ char s_buf[65536];
  __shared__ int  s_eb[128];

  const int tid = threadIdx.x;
  const int w   = tid >> 6;      // 0..7
  const int eh  = w >> 2;        // edge half: rows [eh*64, eh*64+64)
  const int cg  = w & 3;         // col group: cols [cg*64, cg*64+64)
  const int l   = tid & 63;
  const int lo  = l & 15;
  const int hi  = l >> 4;
  const int base = blockIdx.x * 128;

  if (tid < 128) s_eb[tid] = ebatch[base + tid];

  // ---- stage tokens -> LDS bf16 (swizzled) ----
  {
    const float4* g = (const float4*)rel_tok + (size_t)base * 32;
#pragma unroll
    for (int i = 0; i < 8; ++i) {
      int idx = tid + i * 512;          // over [128][32] float4
      int row = idx >> 5, c4 = idx & 31;
      float4 v = g[idx];
      bf16x4 b; b[0] = (bf16)v.x; b[1] = (bf16)v.y; b[2] = (bf16)v.z; b[3] = (bf16)v.w;
      int off = row * 256 + ((c4 * 8) ^ ((row & 7) << 4));
      *(bf16x4*)(s_buf + off) = b;
    }
#pragma unroll
    for (int i = 0; i < 8; ++i) {
      int idx = tid + i * 512;
      int row = idx >> 5, c4 = idx & 31;
      int tail = tail_idx[base + row];  // 32 lanes same addr
      float4 v = ((const float4*)node_tok)[(size_t)tail * 32 + c4];
      bf16x4 b; b[0] = (bf16)v.x; b[1] = (bf16)v.y; b[2] = (bf16)v.z; b[3] = (bf16)v.w;
      int off = 32768 + row * 256 + ((c4 * 8) ^ ((row & 7) << 4));
      *(bf16x4*)(s_buf + off) = b;
    }
  }
  __syncthreads();                       // B_a: tokens + s_eb visible

  const f32x4 zero4 = {0.f, 0.f, 0.f, 0.f};
  const int h1 = cg >> 1;                // GEMM1 half this wave computes

  // ---- GEMM1 (swapped): acc1[ai][bj] = W-frag x token-frag ----
  f32x4 acc1[4][4];
#pragma unroll
  for (int ai = 0; ai < 4; ++ai)
#pragma unroll
    for (int bj = 0; bj < 4; ++bj) acc1[ai][bj] = zero4;

  {
    const bf16* pw = pk1 + cg * 8192 + l * 8;   // [kk][ai] stride 512 elem
#pragma unroll
    for (int kk = 0; kk < 4; ++kk) {
      bf16x8 a[4];
#pragma unroll
      for (int ai = 0; ai < 4; ++ai)
        a[ai] = *(const bf16x8*)(pw + (kk * 4 + ai) * 512);
#pragma unroll
      for (int bj = 0; bj < 4; ++bj) {
        int e = eh * 64 + bj * 16 + lo;
        bf16x8 b = *(const bf16x8*)(s_buf + h1 * 32768 + e * 256 +
                                    ((kk * 64 + hi * 16) ^ ((e & 7) << 4)));
#pragma unroll
        for (int ai = 0; ai < 4; ++ai)
          acc1[ai][bj] = __builtin_amdgcn_mfma_f32_16x16x32_bf16(a[ai], b, acc1[ai][bj], 0, 0, 0);
      }
    }
  }
  __syncthreads();                       // B_b: all token reads done

  // gate + pack -> AK over the token buffer (acc still in regs)
#pragma unroll
  for (int bj = 0; bj < 4; ++bj) {
    int e = eh * 64 + bj * 16 + lo;
    int qrow = s_eb[e] * 256;
#pragma unroll
    for (int ai = 0; ai < 4; ++ai) {
      int col0 = cg * 64 + ai * 16 + hi * 4;
      float4 g = *(const float4*)(qgf + qrow + col0);
      bf16x4 pk;
      pk[0] = (bf16)(acc1[ai][bj][0] * g.x);
      pk[1] = (bf16)(acc1[ai][bj][1] * g.y);
      pk[2] = (bf16)(acc1[ai][bj][2] * g.z);
      pk[3] = (bf16)(acc1[ai][bj][3] * g.w);
      int off = e * 512 + ((2 * col0) ^ ((e & 7) << 4));
      *(bf16x4*)(s_buf + off) = pk;
    }
  }
  __syncthreads();                       // B_c: AK visible

  // ---- GEMM2 (swapped): H^T frags = W1 x AK^T, K=256 ----
  f32x4 acc2[4][4];
#pragma unroll
  for (int ai = 0; ai < 4; ++ai)
#pragma unroll
    for (int bj = 0; bj < 4; ++bj) acc2[ai][bj] = zero4;

  {
    const bf16* pw = pk2 + cg * 16384 + l * 8;
#pragma unroll
    for (int kk = 0; kk < 8; ++kk) {
      bf16x8 a[4];
#pragma unroll
      for (int ai = 0; ai < 4; ++ai)
        a[ai] = *(const bf16x8*)(pw + (kk * 4 + ai) * 512);
#pragma unroll
      for (int bj = 0; bj < 4; ++bj) {
        int e = eh * 64 + bj * 16 + lo;
        bf16x8 b = *(const bf16x8*)(s_buf + e * 512 +
                                    ((kk * 64 + hi * 16) ^ ((e & 7) << 4)));
#pragma unroll
        for (int ai = 0; ai < 4; ++ai)
          acc2[ai][bj] = __builtin_amdgcn_mfma_f32_16x16x32_bf16(a[ai], b, acc2[ai][bj], 0, 0, 0);
      }
    }
  }
  __syncthreads();                       // B_d: all AK reads done

  // gelu + bias -> H (in place over AK rows of own edge half)
  {
    float4 b1v[4];
#pragma unroll
    for (int ai = 0; ai < 4; ++ai)
      b1v[ai] = *(const float4*)(b1 + cg * 64 + ai * 16 + hi * 4);
#pragma unroll
    for (int bj = 0; bj < 4; ++bj) {
      int e = eh * 64 + bj * 16 + lo;
#pragma unroll
      for (int ai = 0; ai < 4; ++ai) {
        int col0 = cg * 64 + ai * 16 + hi * 4;
        bf16x4 pk;
        pk[0] = (bf16)gelu_fast(acc2[ai][bj][0] + b1v[ai].x);
        pk[1] = (bf16)gelu_fast(acc2[ai][bj][1] + b1v[ai].y);
        pk[2] = (bf16)gelu_fast(acc2[ai][bj][2] + b1v[ai].z);
        pk[3] = (bf16)gelu_fast(acc2[ai][bj][3] + b1v[ai].w);
        int off = e * 512 + ((2 * col0) ^ ((e & 7) << 4));
        *(bf16x4*)(s_buf + off) = pk;
      }
    }
  }
  __syncthreads();                       // B_e: H visible

  // ---- GEMM3 (swapped): out^T frags = W2 x H^T, K=256 ----
  f32x4 acc3[4][4];
#pragma unroll
  for (int ai = 0; ai < 4; ++ai)
#pragma unroll
    for (int bj = 0; bj < 4; ++bj) acc3[ai][bj] = zero4;

  {
    const bf16* pw = pk3 + cg * 16384 + l * 8;
#pragma unroll
    for (int kk = 0; kk < 8; ++kk) {
      bf16x8 a[4];
#pragma unroll
      for (int ai = 0; ai < 4; ++ai)
        a[ai] = *(const bf16x8*)(pw + (kk * 4 + ai) * 512);
#pragma unroll
      for (int bj = 0; bj < 4; ++bj) {
        int e = eh * 64 + bj * 16 + lo;
        bf16x8 b = *(const bf16x8*)(s_buf + e * 512 +
                                    ((kk * 64 + hi * 16) ^ ((e & 7) << 4)));
#pragma unroll
        for (int ai = 0; ai < 4; ++ai)
          acc3[ai][bj] = __builtin_amdgcn_mfma_f32_16x16x32_bf16(a[ai], b, acc3[ai][bj], 0, 0, 0);
      }
    }
  }

  // bias + store: one float4 per fragment (lanes hi=0..3 form 64B runs)
  {
    float4 b2v[4];
#pragma unroll
    for (int ai = 0; ai < 4; ++ai)
      b2v[ai] = *(const float4*)(b2 + cg * 64 + ai * 16 + hi * 4);
#pragma unroll
    for (int bj = 0; bj < 4; ++bj) {
      int e = eh * 64 + bj * 16 + lo;
#pragma unroll
      for (int ai = 0; ai < 4; ++ai) {
        int col0 = cg * 64 + ai * 16 + hi * 4;
        float4 o;
        o.x = acc3[ai][bj][0] + b2v[ai].x;
        o.y = acc3[ai][bj][1] + b2v[ai].y;
        o.z = acc3[ai][bj][2] + b2v[ai].z;
        o.w = acc3[ai][bj][3] + b2v[ai].w;
        *(float4*)(out + (size_t)(base + e) * 256 + col0) = o;
      }
    }
  }
}

extern "C" void kernel_launch(void* const* d_in, const int* in_sizes, int n_in,
                              void* d_out, int out_size, void* d_ws, size_t ws_size,
                              hipStream_t stream) {
  const float* rel    = (const float*)d_in[0];
  const float* node   = (const float*)d_in[1];
  const int*   eidx   = (const int*)d_in[2];
  const float* quest  = (const float*)d_in[3];
  const int*   ebat   = (const int*)d_in[4];
  const float* Wrel   = (const float*)d_in[5];
  const float* Wnode  = (const float*)d_in[6];
  const float* Wq     = (const float*)d_in[7];
  const float* W1     = (const float*)d_in[8];
  const float* bias1  = (const float*)d_in[9];
  const float* W2     = (const float*)d_in[10];
  const float* bias2  = (const float*)d_in[11];
  float* outp = (float*)d_out;
  bf16* ws = (bf16*)d_ws;
  float* qgf = (float*)(ws + WS_QG_F);

  const int E = in_sizes[4];  // 400000

  prep_weights<<<640, 256, 0, stream>>>(Wrel, Wnode, W1, W2, ws);
  prep_qg<<<64, 256, 0, stream>>>(quest, Wq, qgf);
  fused_main<<<E / 128, 512, 0, stream>>>(
      rel, node, eidx + E, ebat,
      ws + WS_PK1, ws + WS_PK2, ws + WS_PK3, qgf,
      bias1, bias2, outp);
}